// Round 8
// baseline (245.947 us; speedup 1.0000x reference)
//
#include <hip/hip_runtime.h>
#include <math.h>

#define NEG_SLOPE 0.2f
constexpr int BS_SCAN = 1024;
constexpr int HB_MAX = 160;   // max hist blocks (E <= 160*4096)
constexpr int WPB    = 32;    // words per scanT block

typedef __attribute__((ext_vector_type(8))) short bfrag;   // 8 x bf16
typedef __attribute__((ext_vector_type(4))) float f32x4;

__device__ __forceinline__ float lrelu(float x) { return x > 0.f ? x : NEG_SLOPE * x; }

__device__ __forceinline__ unsigned short f2bf(float f) {
    union { float f; unsigned u; } v; v.f = f;
    unsigned r = v.u + 0x7fffu + ((v.u >> 16) & 1u);   // RNE
    return (unsigned short)(r >> 16);
}
__device__ __forceinline__ float bf2f_lo(unsigned p) { union { unsigned u; float f; } v; v.u = p << 16; return v.f; }
__device__ __forceinline__ float bf2f_hi(unsigned p) { union { unsigned u; float f; } v; v.u = p & 0xffff0000u; return v.f; }

// ---------------- W swizzle body ----------------
__device__ __forceinline__ void wswz_body(const float* __restrict__ W, unsigned short* __restrict__ out,
                                          int DOUT, int tid) {
    int lane = tid & 63;
    int g = tid >> 6;
    int NT = DOUT >> 4;
    int tile = g % NT, kstep = g / NT;
    int q = lane >> 4, c = lane & 15;
    int n_ = tile * 16 + c;
    unsigned short v[8];
#pragma unroll
    for (int j = 0; j < 8; ++j) {
        int k = kstep * 32 + q * 8 + j;
        v[j] = f2bf(W[k * DOUT + n_]);
    }
    uint4 o;
    o.x = (unsigned)v[0] | ((unsigned)v[1] << 16);
    o.y = (unsigned)v[2] | ((unsigned)v[3] << 16);
    o.z = (unsigned)v[4] | ((unsigned)v[5] << 16);
    o.w = (unsigned)v[6] | ((unsigned)v[7] << 16);
    *(uint4*)(out + (size_t)tid * 8) = o;
}

// ---------------- K1: per-block LDS histogram (rank capture, NO device atomics) + W swizzles ------
__global__ __launch_bounds__(256) void histswz_kernel(
    const int* __restrict__ dstv, unsigned* __restrict__ hist32, unsigned char* __restrict__ rank8,
    int E, int hb, int nw, int* __restrict__ done,
    const float* __restrict__ W0, const float* __restrict__ W1, const float* __restrict__ W2,
    unsigned short* __restrict__ wz0, unsigned short* __restrict__ wz1, unsigned short* __restrict__ wz2)
{
    __shared__ unsigned bins[12544];   // 50 KB (n=50000 -> 12544 packed words)
    int b = blockIdx.x;
    if (b >= hb) {
        int wb = b - hb;
        if (wb == 0 && threadIdx.x == 0) { done[0] = 0; done[1] = 0; }   // reset rendezvous counters
        if (wb < 8)       wswz_body(W0, wz0, 128, wb * 256 + threadIdx.x);
        else if (wb < 16) wswz_body(W1, wz1, 128, (wb - 8) * 256 + threadIdx.x);
        else {
            int tid = (wb - 16) * 256 + threadIdx.x;
            if (tid < 1024) wswz_body(W2, wz2, 64, tid);
        }
        return;
    }
    int tid = threadIdx.x;
    int nw4 = nw >> 2;
    bool v4ok = (nw & 3) == 0;
    if (v4ok) {
        uint4 z4; z4.x = z4.y = z4.z = z4.w = 0u;
        uint4* b4 = (uint4*)bins;
        for (int i = tid; i < nw4; i += 256) b4[i] = z4;
    } else {
        for (int i = tid; i < nw; i += 256) bins[i] = 0u;
    }
    __syncthreads();
    int base = b * 4096;
#pragma unroll
    for (int j = 0; j < 4; ++j) {
        int e0 = base + j * 1024 + tid * 4;
        if (e0 + 3 < E) {
            int4 d4 = *(const int4*)(dstv + e0);
            unsigned r0, r1, r2, r3;
            { int sh = (d4.x & 3) * 8; r0 = (atomicAdd(&bins[d4.x >> 2], 1u << sh) >> sh) & 0xffu; }
            { int sh = (d4.y & 3) * 8; r1 = (atomicAdd(&bins[d4.y >> 2], 1u << sh) >> sh) & 0xffu; }
            { int sh = (d4.z & 3) * 8; r2 = (atomicAdd(&bins[d4.z >> 2], 1u << sh) >> sh) & 0xffu; }
            { int sh = (d4.w & 3) * 8; r3 = (atomicAdd(&bins[d4.w >> 2], 1u << sh) >> sh) & 0xffu; }
            *(unsigned*)(rank8 + e0) = r0 | (r1 << 8) | (r2 << 16) | (r3 << 24);
        } else {
            for (int k = 0; k < 4; ++k) {
                int e = e0 + k;
                if (e < E) {
                    int d = dstv[e];
                    int sh = (d & 3) * 8;
                    rank8[e] = (unsigned char)((atomicAdd(&bins[d >> 2], 1u << sh) >> sh) & 0xffu);
                }
            }
        }
    }
    __syncthreads();
    unsigned* hrow = hist32 + (size_t)b * nw;
    if (v4ok) {
        uint4* h4 = (uint4*)hrow;
        const uint4* s4 = (const uint4*)bins;
        for (int i = tid; i < nw4; i += 256) h4[i] = s4[i];
    } else {
        for (int i = tid; i < nw; i += 256) hrow[i] = bins[i];
    }
}

// ---------------- GEMM body (bf16 MFMA) + attention dots, 2-chunk LDS ----------------
template<int DOUT, bool ABF>
__device__ __forceinline__ void gemm_body(
    int bid, const void* __restrict__ Xv, const unsigned short* __restrict__ Wswz,
    const float* __restrict__ avs, const float* __restrict__ avd,
    unsigned* __restrict__ Hout, float* __restrict__ as_out, float* __restrict__ ad_out,
    int n, float* __restrict__ smemw)
{
    constexpr int NT = DOUT / 16;
    constexpr int NCH = NT / 4;          // 2 for DOUT=128, 1 for DOUT=64
    int lane = threadIdx.x & 63;
    int w = threadIdx.x >> 6;
    int q = lane >> 4, c = lane & 15;
    int rowbase = bid * 64 + w * 16;
    int arow = rowbase + c;

    f32x4 acc[NT];
#pragma unroll
    for (int t = 0; t < NT; ++t) acc[t] = (f32x4){0.f, 0.f, 0.f, 0.f};

#pragma unroll
    for (int ks = 0; ks < 4; ++ks) {
        bfrag a = (bfrag)0;
        int k0 = ks * 32 + q * 8;
        if (ABF) {
            if (arow < n) a = *(const bfrag*)((const unsigned short*)Xv + (size_t)arow * 128 + k0);
        } else {
            if (arow < n) {
                const float* xp = (const float*)Xv + (size_t)arow * 128 + k0;
                float4 x0 = *(const float4*)xp, x1 = *(const float4*)(xp + 4);
                a[0] = (short)f2bf(x0.x); a[1] = (short)f2bf(x0.y);
                a[2] = (short)f2bf(x0.z); a[3] = (short)f2bf(x0.w);
                a[4] = (short)f2bf(x1.x); a[5] = (short)f2bf(x1.y);
                a[6] = (short)f2bf(x1.z); a[7] = (short)f2bf(x1.w);
            }
        }
#pragma unroll
        for (int t = 0; t < NT; ++t) {
            bfrag b = *(const bfrag*)(Wswz + ((size_t)(ks * NT + t) * 64 + lane) * 8);
            acc[t] = __builtin_amdgcn_mfma_f32_16x16x32_bf16(a, b, acc[t], 0, 0, 0);
        }
    }

    // per-wave transpose buffer: 16 rows x 68 floats (64 cols + pad) = 4352 B/wave
    float* sm = smemw + w * (16 * 68);
    int dr = lane >> 2;
    int c0 = (lane & 3) * 16;
    float s = 0.f, d = 0.f;

#pragma unroll
    for (int ch = 0; ch < NCH; ++ch) {
        if (ch) {
            // drain chunk-0 LDS reads before overwriting (WAR within wave)
            asm volatile("s_waitcnt lgkmcnt(0)" ::: "memory");
            __builtin_amdgcn_wave_barrier();
        }
#pragma unroll
        for (int t = 0; t < 4; ++t)
#pragma unroll
            for (int r = 0; r < 4; ++r)
                sm[(q * 4 + r) * 68 + t * 16 + c] = acc[ch * 4 + t][r];
        __builtin_amdgcn_wave_barrier();

        // bf16 store of this 64-col chunk
#pragma unroll
        for (int it = 0; it < 4; ++it) {
            int r = it * 4 + q;
            int grow = rowbase + r;
            float4 v = *(const float4*)(sm + r * 68 + c * 4);
            uint2 o;
            o.x = (unsigned)f2bf(v.x) | ((unsigned)f2bf(v.y) << 16);
            o.y = (unsigned)f2bf(v.z) | ((unsigned)f2bf(v.w) << 16);
            if (grow < n) *(uint2*)(Hout + (size_t)grow * (DOUT / 2) + ch * 32 + c * 2) = o;
        }
        // attention-dot partials for this chunk
#pragma unroll
        for (int j = 0; j < 16; j += 4) {
            float4 hv = *(const float4*)(sm + dr * 68 + c0 + j);
            float4 av = *(const float4*)(avs + ch * 64 + c0 + j);
            float4 dv = *(const float4*)(avd + ch * 64 + c0 + j);
            s += hv.x * av.x + hv.y * av.y + hv.z * av.z + hv.w * av.w;
            d += hv.x * dv.x + hv.y * dv.y + hv.z * dv.z + hv.w * dv.w;
        }
    }

    s += __shfl_down(s, 2); s += __shfl_down(s, 1);
    d += __shfl_down(d, 2); d += __shfl_down(d, 1);
    int grow = rowbase + dr;
    if ((lane & 3) == 0 && grow < n) { as_out[grow] = s; ad_out[grow] = d; }
}

// ---------------- K2: LDS-transpose column scan of histograms + layer-0 GEMM, one dispatch ------
__global__ __launch_bounds__(256) void scangemm0_kernel(
    const unsigned* __restrict__ hist32, unsigned* __restrict__ off32,
    int* __restrict__ counts, int hb, int nw, int sb,
    const float* __restrict__ X, const unsigned short* __restrict__ wz0,
    const float* __restrict__ avs, const float* __restrict__ avd,
    unsigned* __restrict__ Hout, float* __restrict__ as_out, float* __restrict__ ad_out, int n)
{
    __shared__ unsigned smem[HB_MAX * (WPB + 1)];   // 160*33*4 = 21120 B
    int b = blockIdx.x;
    if (b < sb) {
        unsigned (*tile)[WPB + 1] = (unsigned (*)[WPB + 1])smem;
        int tid = threadIdx.x;
        int w0 = b * WPB;
        int wl = tid & 31;
        int w = w0 + wl;
        for (int r = tid >> 5; r < hb; r += 8)
            tile[r][wl] = (w < nw) ? hist32[(size_t)r * nw + w] : 0u;
        __syncthreads();
        if (tid < WPB) {
            unsigned run = 0;
            for (int r = 0; r < hb; ++r) {
                unsigned v = tile[r][tid];
                tile[r][tid] = run;    // exclusive prefix per 8-bit field
                run += v;              // no inter-field carry: per-node totals << 256
            }
            int ww = w0 + tid;
            if (ww < nw) {
                int i0 = ww * 4;
                int4 cv;
                cv.x = (int)(run & 0xffu);         cv.y = (int)((run >> 8) & 0xffu);
                cv.z = (int)((run >> 16) & 0xffu); cv.w = (int)((run >> 24) & 0xffu);
                if (i0 + 3 < n) *(int4*)(counts + i0) = cv;
                else {
                    if (i0 < n)     counts[i0]     = cv.x;
                    if (i0 + 1 < n) counts[i0 + 1] = cv.y;
                    if (i0 + 2 < n) counts[i0 + 2] = cv.z;
                    if (i0 + 3 < n) counts[i0 + 3] = cv.w;
                }
            }
        }
        __syncthreads();
        for (int r = tid >> 5; r < hb; r += 8)
            if (w < nw) off32[(size_t)r * nw + w] = tile[r][wl];
        return;
    }
    gemm_body<128, false>(b - sb, X, wz0, avs, avd, Hout, as_out, ad_out, n, (float*)smem);
}

// ---------------- K3: row_ptr scan + degree-bucket perm + scatter, ONE dispatch ----------------
// Roles by blockIdx: [0,nb) scan (publish row_ptr via done[1]); nb: perm build (independent);
// (nb, nb+scb]: scatter (spin on done[1]). 197 blocks @1024thr, all co-resident (cap >= 256).
__global__ __launch_bounds__(1024) void csrfinish_kernel(
    const int* __restrict__ counts, int* __restrict__ row_ptr,
    int* __restrict__ totals, int* __restrict__ done, int* __restrict__ perm,
    const int* __restrict__ ei, const unsigned char* __restrict__ rank8,
    const unsigned* __restrict__ off32, unsigned short* __restrict__ col,
    int n, int E, int nb, int nw)
{
    __shared__ int sm[BS_SCAN];
    __shared__ int s_off;
    int tid = threadIdx.x;
    int b = blockIdx.x;

    if (b < nb) {
        // ---- scan role (R7-proven publish+spin, totals via done[0], row_ptr via done[1]) ----
        int i = b * BS_SCAN + tid;
        int v = (i < n) ? counts[i] : 0;
        int val = v;
        sm[tid] = val;
        for (int off = 1; off < BS_SCAN; off <<= 1) {
            __syncthreads();
            int t = (tid >= off) ? sm[tid - off] : 0;
            __syncthreads();
            val += t; sm[tid] = val;
        }
        if (tid == BS_SCAN - 1) {
            totals[b] = val;
            __threadfence();
            atomicAdd(&done[0], 1);
        }
        if (tid < 64) {
            while (atomicAdd(&done[0], 0) < nb) {}
            __threadfence();
            int t = (tid < b && tid < nb) ? totals[tid] : 0;
#pragma unroll
            for (int off = 32; off; off >>= 1) t += __shfl_xor(t, off);
            if (tid == 0) s_off = t;
        }
        __syncthreads();
        if (i < n) row_ptr[i] = val - v + s_off;
        if (i == 0) row_ptr[n] = E;
        __syncthreads();
        if (tid == 0) {
            __threadfence();
            atomicAdd(&done[1], 1);    // row_ptr published
        }
        return;
    }

    if (b == nb) {
        // ---- perm role: 32-bucket degree sort (stable within bucket) ----
        __shared__ int bh[32];
        if (tid < 32) bh[tid] = 0;
        __syncthreads();
        for (int i = tid; i < n; i += 1024) {
            int k = counts[i]; k = k > 31 ? 31 : k;
            atomicAdd(&bh[k], 1);
        }
        __syncthreads();
        if (tid == 0) {
            int run = 0;
            for (int k = 0; k < 32; ++k) { int t = bh[k]; bh[k] = run; run += t; }
        }
        __syncthreads();
        for (int i = tid; i < n; i += 1024) {
            int k = counts[i]; k = k > 31 ? 31 : k;
            int pos = atomicAdd(&bh[k], 1);
            perm[pos] = i;
        }
        return;
    }

    // ---- scatter role: wait for row_ptr, then atomic-free scatter (4096 edges/block) ----
    if (tid == 0) {
        while (atomicAdd(&done[1], 0) < nb) {}
        __threadfence();
    }
    __syncthreads();
    int e0 = (b - nb - 1) * 4096 + tid * 4;
    if (e0 + 3 < E) {
        int4 s4 = *(const int4*)(ei + e0);
        int4 d4 = *(const int4*)(ei + E + e0);
        unsigned r4 = *(const unsigned*)(rank8 + e0);
        size_t bb = (size_t)(e0 >> 12) * nw;   // e0..e0+3 share the 4096-edge chunk
        unsigned o0 = (off32[bb + (d4.x >> 2)] >> ((d4.x & 3) * 8)) & 0xffu;
        unsigned o1 = (off32[bb + (d4.y >> 2)] >> ((d4.y & 3) * 8)) & 0xffu;
        unsigned o2 = (off32[bb + (d4.z >> 2)] >> ((d4.z & 3) * 8)) & 0xffu;
        unsigned o3 = (off32[bb + (d4.w >> 2)] >> ((d4.w & 3) * 8)) & 0xffu;
        col[row_ptr[d4.x] + (int)o0 + (int)(r4 & 0xffu)]         = (unsigned short)s4.x;
        col[row_ptr[d4.y] + (int)o1 + (int)((r4 >> 8) & 0xffu)]  = (unsigned short)s4.y;
        col[row_ptr[d4.z] + (int)o2 + (int)((r4 >> 16) & 0xffu)] = (unsigned short)s4.z;
        col[row_ptr[d4.w] + (int)o3 + (int)((r4 >> 24) & 0xffu)] = (unsigned short)s4.w;
    } else {
        for (int k = 0; k < 4; ++k) {
            int e = e0 + k;
            if (e < E) {
                int d = ei[E + e];
                unsigned o = (off32[(size_t)(e >> 12) * nw + (d >> 2)] >> ((d & 3) * 8)) & 0xffu;
                col[row_ptr[d] + (int)o + (int)rank8[e]] = (unsigned short)ei[e];
            }
        }
    }
}

// ---------------- standalone GEMM layers 1/2 (A = bf16 global) ----------------
template<int DOUT>
__global__ __launch_bounds__(256) void gemm_kernel(
    const unsigned* __restrict__ Xb, const unsigned short* __restrict__ Wswz,
    const float* __restrict__ avs, const float* __restrict__ avd,
    unsigned* __restrict__ Hout, float* __restrict__ as_out, float* __restrict__ ad_out, int n)
{
    __shared__ float smem[4 * 16 * 68];
    gemm_body<DOUT, true>(blockIdx.x, Xb, Wswz, avs, avd, Hout, as_out, ad_out, n, smem);
}

// ---------------- aggregation, 128-wide bf16 h, SiLU, bf16 out ----------------
// 16 lanes per node, nodes taken in degree-sorted perm order (waves see uniform degree).
__global__ __launch_bounds__(256) void agg128_kernel(
    const unsigned* __restrict__ Hb, const float* __restrict__ as_v,
    const float* __restrict__ ad_v, const float* __restrict__ bias,
    const int* __restrict__ row_ptr, const unsigned short* __restrict__ col,
    const int* __restrict__ perm, unsigned* __restrict__ outb, int n)
{
    int lane = threadIdx.x & 63;
    int g = lane >> 4, i = lane & 15;
    int raw = blockIdx.x * 16 + (threadIdx.x >> 6) * 4 + g;
    if (raw >= n) return;
    int node = perm[raw];
    int beg = row_ptr[node], end = row_ptr[node + 1];
    float adv = ad_v[node];
    float c_self = __expf(fminf(lrelu(as_v[node] + adv), 60.f));

    uint4 hs = *(const uint4*)(Hb + (size_t)node * 64 + i * 4);
    float acc[8];
    acc[0] = c_self * bf2f_lo(hs.x); acc[1] = c_self * bf2f_hi(hs.x);
    acc[2] = c_self * bf2f_lo(hs.y); acc[3] = c_self * bf2f_hi(hs.y);
    acc[4] = c_self * bf2f_lo(hs.z); acc[5] = c_self * bf2f_hi(hs.z);
    acc[6] = c_self * bf2f_lo(hs.w); acc[7] = c_self * bf2f_hi(hs.w);
    float dsum = (i == 0) ? c_self : 0.f;
    int lanebase = g * 16;

    for (int cb = beg; cb < end; cb += 16) {
        int idx = cb + i;
        int sreg = 0; float creg = 0.f;
        if (idx < end) {
            sreg = col[idx];
            creg = __expf(fminf(lrelu(as_v[sreg] + adv), 60.f));
        }
        dsum += creg;
        int cnt = end - cb; if (cnt > 16) cnt = 16;
        for (int k = 0; k < cnt; k += 4) {
            int s0 = __shfl(sreg, lanebase + k);
            int s1 = __shfl(sreg, lanebase + k + 1);
            int s2 = __shfl(sreg, lanebase + k + 2);
            int s3 = __shfl(sreg, lanebase + k + 3);
            float c0 = __shfl(creg, lanebase + k);       // lanes >= cnt carry creg=0
            float c1 = __shfl(creg, lanebase + k + 1);
            float c2 = __shfl(creg, lanebase + k + 2);
            float c3 = __shfl(creg, lanebase + k + 3);
            uint4 h0 = *(const uint4*)(Hb + (size_t)s0 * 64 + i * 4);
            uint4 h1 = *(const uint4*)(Hb + (size_t)s1 * 64 + i * 4);
            uint4 h2 = *(const uint4*)(Hb + (size_t)s2 * 64 + i * 4);
            uint4 h3 = *(const uint4*)(Hb + (size_t)s3 * 64 + i * 4);
            acc[0] += c0 * bf2f_lo(h0.x); acc[1] += c0 * bf2f_hi(h0.x);
            acc[2] += c0 * bf2f_lo(h0.y); acc[3] += c0 * bf2f_hi(h0.y);
            acc[4] += c0 * bf2f_lo(h0.z); acc[5] += c0 * bf2f_hi(h0.z);
            acc[6] += c0 * bf2f_lo(h0.w); acc[7] += c0 * bf2f_hi(h0.w);
            acc[0] += c1 * bf2f_lo(h1.x); acc[1] += c1 * bf2f_hi(h1.x);
            acc[2] += c1 * bf2f_lo(h1.y); acc[3] += c1 * bf2f_hi(h1.y);
            acc[4] += c1 * bf2f_lo(h1.z); acc[5] += c1 * bf2f_hi(h1.z);
            acc[6] += c1 * bf2f_lo(h1.w); acc[7] += c1 * bf2f_hi(h1.w);
            acc[0] += c2 * bf2f_lo(h2.x); acc[1] += c2 * bf2f_hi(h2.x);
            acc[2] += c2 * bf2f_lo(h2.y); acc[3] += c2 * bf2f_hi(h2.y);
            acc[4] += c2 * bf2f_lo(h2.z); acc[5] += c2 * bf2f_hi(h2.z);
            acc[6] += c2 * bf2f_lo(h2.w); acc[7] += c2 * bf2f_hi(h2.w);
            acc[0] += c3 * bf2f_lo(h3.x); acc[1] += c3 * bf2f_hi(h3.x);
            acc[2] += c3 * bf2f_lo(h3.y); acc[3] += c3 * bf2f_hi(h3.y);
            acc[4] += c3 * bf2f_lo(h3.z); acc[5] += c3 * bf2f_hi(h3.z);
            acc[6] += c3 * bf2f_lo(h3.w); acc[7] += c3 * bf2f_hi(h3.w);
        }
    }

#pragma unroll
    for (int off = 8; off; off >>= 1) dsum += __shfl_xor(dsum, off);
    float inv = 1.f / dsum;

    float4 b0v = *(const float4*)(bias + i * 8);
    float4 b1v = *(const float4*)(bias + i * 8 + 4);
    float v0 = acc[0] * inv + b0v.x, v1 = acc[1] * inv + b0v.y;
    float v2 = acc[2] * inv + b0v.z, v3 = acc[3] * inv + b0v.w;
    float v4 = acc[4] * inv + b1v.x, v5 = acc[5] * inv + b1v.y;
    float v6 = acc[6] * inv + b1v.z, v7 = acc[7] * inv + b1v.w;
    v0 /= (1.f + __expf(-v0)); v1 /= (1.f + __expf(-v1));
    v2 /= (1.f + __expf(-v2)); v3 /= (1.f + __expf(-v3));
    v4 /= (1.f + __expf(-v4)); v5 /= (1.f + __expf(-v5));
    v6 /= (1.f + __expf(-v6)); v7 /= (1.f + __expf(-v7));
    uint4 o;
    o.x = (unsigned)f2bf(v0) | ((unsigned)f2bf(v1) << 16);
    o.y = (unsigned)f2bf(v2) | ((unsigned)f2bf(v3) << 16);
    o.z = (unsigned)f2bf(v4) | ((unsigned)f2bf(v5) << 16);
    o.w = (unsigned)f2bf(v6) | ((unsigned)f2bf(v7) << 16);
    *(uint4*)(outb + (size_t)node * 64 + i * 4) = o;
}

// ---------------- final aggregation: bf16 h [n,64], log_softmax, fp32 out ----------------
__global__ __launch_bounds__(256) void agg64_kernel(
    const unsigned* __restrict__ Hb, const float* __restrict__ as_v,
    const float* __restrict__ ad_v, const float* __restrict__ bias,
    const int* __restrict__ row_ptr, const unsigned short* __restrict__ col,
    const int* __restrict__ perm, float* __restrict__ out, int n)
{
    int lane = threadIdx.x & 63;
    int g = lane >> 4, i = lane & 15;
    int raw = blockIdx.x * 16 + (threadIdx.x >> 6) * 4 + g;
    if (raw >= n) return;
    int node = perm[raw];
    int beg = row_ptr[node], end = row_ptr[node + 1];
    float adv = ad_v[node];
    float c_self = __expf(fminf(lrelu(as_v[node] + adv), 60.f));

    uint2 hs = *(const uint2*)(Hb + (size_t)node * 32 + i * 2);
    float acc[4];
    acc[0] = c_self * bf2f_lo(hs.x); acc[1] = c_self * bf2f_hi(hs.x);
    acc[2] = c_self * bf2f_lo(hs.y); acc[3] = c_self * bf2f_hi(hs.y);
    float dsum = (i == 0) ? c_self : 0.f;
    int lanebase = g * 16;

    for (int cb = beg; cb < end; cb += 16) {
        int idx = cb + i;
        int sreg = 0; float creg = 0.f;
        if (idx < end) {
            sreg = col[idx];
            creg = __expf(fminf(lrelu(as_v[sreg] + adv), 60.f));
        }
        dsum += creg;
        int cnt = end - cb; if (cnt > 16) cnt = 16;
        for (int k = 0; k < cnt; k += 4) {
            int s0 = __shfl(sreg, lanebase + k);
            int s1 = __shfl(sreg, lanebase + k + 1);
            int s2 = __shfl(sreg, lanebase + k + 2);
            int s3 = __shfl(sreg, lanebase + k + 3);
            float c0 = __shfl(creg, lanebase + k);
            float c1 = __shfl(creg, lanebase + k + 1);
            float c2 = __shfl(creg, lanebase + k + 2);
            float c3 = __shfl(creg, lanebase + k + 3);
            uint2 h0 = *(const uint2*)(Hb + (size_t)s0 * 32 + i * 2);
            uint2 h1 = *(const uint2*)(Hb + (size_t)s1 * 32 + i * 2);
            uint2 h2 = *(const uint2*)(Hb + (size_t)s2 * 32 + i * 2);
            uint2 h3 = *(const uint2*)(Hb + (size_t)s3 * 32 + i * 2);
            acc[0] += c0 * bf2f_lo(h0.x); acc[1] += c0 * bf2f_hi(h0.x);
            acc[2] += c0 * bf2f_lo(h0.y); acc[3] += c0 * bf2f_hi(h0.y);
            acc[0] += c1 * bf2f_lo(h1.x); acc[1] += c1 * bf2f_hi(h1.x);
            acc[2] += c1 * bf2f_lo(h1.y); acc[3] += c1 * bf2f_hi(h1.y);
            acc[0] += c2 * bf2f_lo(h2.x); acc[1] += c2 * bf2f_hi(h2.x);
            acc[2] += c2 * bf2f_lo(h2.y); acc[3] += c2 * bf2f_hi(h2.y);
            acc[0] += c3 * bf2f_lo(h3.x); acc[1] += c3 * bf2f_hi(h3.x);
            acc[2] += c3 * bf2f_lo(h3.y); acc[3] += c3 * bf2f_hi(h3.y);
        }
    }

#pragma unroll
    for (int off = 8; off; off >>= 1) dsum += __shfl_xor(dsum, off);
    float inv = 1.f / dsum;

    float4 bv = *(const float4*)(bias + i * 4);
    float v0 = acc[0] * inv + bv.x, v1 = acc[1] * inv + bv.y;
    float v2 = acc[2] * inv + bv.z, v3 = acc[3] * inv + bv.w;
    float mx = fmaxf(fmaxf(v0, v1), fmaxf(v2, v3));
#pragma unroll
    for (int off = 8; off; off >>= 1) mx = fmaxf(mx, __shfl_xor(mx, off));
    float sum = __expf(v0 - mx) + __expf(v1 - mx) + __expf(v2 - mx) + __expf(v3 - mx);
#pragma unroll
    for (int off = 8; off; off >>= 1) sum += __shfl_xor(sum, off);
    float ls = mx + logf(sum);
    float4 o = make_float4(v0 - ls, v1 - ls, v2 - ls, v3 - ls);
    *(float4*)(out + (size_t)node * 64 + i * 4) = o;
}

extern "C" void kernel_launch(void* const* d_in, const int* in_sizes, int n_in,
                              void* d_out, int out_size, void* d_ws, size_t ws_size,
                              hipStream_t stream) {
    const float* x   = (const float*)d_in[0];
    const int*   ei  = (const int*)d_in[1];
    const float* W0  = (const float*)d_in[2];
    const float* as0 = (const float*)d_in[3];
    const float* ad0 = (const float*)d_in[4];
    const float* b0  = (const float*)d_in[5];
    const float* W1  = (const float*)d_in[6];
    const float* as1 = (const float*)d_in[7];
    const float* ad1 = (const float*)d_in[8];
    const float* b1  = (const float*)d_in[9];
    const float* W2  = (const float*)d_in[10];
    const float* as2 = (const float*)d_in[11];
    const float* ad2 = (const float*)d_in[12];
    const float* b2  = (const float*)d_in[13];

    int n = in_sizes[0] / 128;
    int E = in_sizes[1] / 2;
    const int* dstv = ei + E;

    int hb = (E + 4095) >> 12;              // histogram blocks (4096 edges each), 147 <= HB_MAX
    int nw = (n + 3) >> 2;                  // packed u32 words (4 nodes per word)

    char* wsp = (char*)d_ws;
    auto alloc = [&](size_t bytes) {
        char* p = wsp;
        wsp += (bytes + 255) & ~(size_t)255;
        return p;
    };
    int*   counts  = (int*)alloc((size_t)n * 4);
    int*   row_ptr = (int*)alloc((size_t)(n + 1) * 4);
    int*   perm    = (int*)alloc((size_t)n * 4);
    int*   totals  = (int*)alloc(256 * 4);
    int*   done    = (int*)alloc(256);
    unsigned* hist32 = (unsigned*)alloc((size_t)hb * nw * 4);
    unsigned* off32  = (unsigned*)alloc((size_t)hb * nw * 4);
    unsigned char* rank8 = (unsigned char*)alloc((size_t)E);
    unsigned short* col = (unsigned short*)alloc((size_t)E * 2);
    unsigned short* wz0 = (unsigned short*)alloc(128 * 128 * 2);
    unsigned short* wz1 = (unsigned short*)alloc(128 * 128 * 2);
    unsigned short* wz2 = (unsigned short*)alloc(128 * 64 * 2);
    unsigned* hb0  = (unsigned*)alloc((size_t)n * 64 * 4);   // [n,128] bf16 (pre-agg h)
    unsigned* hb1  = (unsigned*)alloc((size_t)n * 64 * 4);   // [n,128] bf16
    unsigned* hf   = (unsigned*)alloc((size_t)n * 32 * 4);   // [n,64]  bf16
    unsigned* xb   = (unsigned*)alloc((size_t)n * 64 * 4);   // [n,128] bf16 (agg out)
    float*    asbA = (float*)alloc((size_t)n * 4);
    float*    adbA = (float*)alloc((size_t)n * 4);
    float*    asbB = (float*)alloc((size_t)n * 4);
    float*    adbB = (float*)alloc((size_t)n * 4);

    int gemmb = (n + 63) / 64;
    int nodeb = (n + 15) / 16;              // 16 nodes/block (16 lanes/node)
    int nb  = (n + BS_SCAN - 1) / BS_SCAN;  // 49 <= 64
    int sb  = (nw + WPB - 1) / WPB;         // transpose-scan blocks (392)
    int scb = (E + 4095) / 4096;            // scatter blocks (4096 edges each, 1024 thr)

    // K1: LDS histogram + rank8 (no device atomics), W swizzles + counter-reset riding along
    histswz_kernel<<<hb + 20, 256, 0, stream>>>(dstv, hist32, rank8, E, hb, nw, done,
                                                W0, W1, W2, wz0, wz1, wz2);
    // K2: cross-block offset scan (LDS-transpose, parallel) + layer-0 GEMM + dots
    scangemm0_kernel<<<sb + gemmb, 256, 0, stream>>>(hist32, off32, counts, hb, nw, sb,
                                                     x, wz0, as0, ad0, hb0, asbA, adbA, n);
    // K3: row_ptr scan + degree-perm + scatter, one dispatch (publish+spin, co-resident)
    csrfinish_kernel<<<nb + 1 + scb, 1024, 0, stream>>>(counts, row_ptr, totals, done, perm,
                                                        ei, rank8, off32, col, n, E, nb, nw);
    // layer 0 agg
    agg128_kernel<<<nodeb, 256, 0, stream>>>(hb0, asbA, adbA, b0, row_ptr, col, perm, xb, n);
    // layer 1 GEMM + agg
    gemm_kernel<128><<<gemmb, 256, 0, stream>>>(xb, wz1, as1, ad1, hb1, asbB, adbB, n);
    agg128_kernel<<<nodeb, 256, 0, stream>>>(hb1, asbB, adbB, b1, row_ptr, col, perm, xb, n);
    // layer 2 GEMM + final agg
    gemm_kernel<64><<<gemmb, 256, 0, stream>>>(xb, wz2, as2, ad2, hf, asbA, adbA, n);
    agg64_kernel<<<nodeb, 256, 0, stream>>>(hf, asbA, adbA, b2, row_ptr, col, perm, (float*)d_out, n);
}

// Round 9
// 224.358 us; speedup vs baseline: 1.0962x; 1.0962x over previous
//
#include <hip/hip_runtime.h>
#include <math.h>

#define NEG_SLOPE 0.2f
constexpr int BS_SCAN = 1024;
constexpr int HB_MAX = 160;   // max hist blocks (E <= 160*4096)
constexpr int WPB    = 32;    // words per scanT block

typedef __attribute__((ext_vector_type(8))) short bfrag;   // 8 x bf16
typedef __attribute__((ext_vector_type(4))) float f32x4;

__device__ __forceinline__ float lrelu(float x) { return x > 0.f ? x : NEG_SLOPE * x; }

__device__ __forceinline__ unsigned short f2bf(float f) {
    union { float f; unsigned u; } v; v.f = f;
    unsigned r = v.u + 0x7fffu + ((v.u >> 16) & 1u);   // RNE
    return (unsigned short)(r >> 16);
}
__device__ __forceinline__ float bf2f_lo(unsigned p) { union { unsigned u; float f; } v; v.u = p << 16; return v.f; }
__device__ __forceinline__ float bf2f_hi(unsigned p) { union { unsigned u; float f; } v; v.u = p & 0xffff0000u; return v.f; }

// ---------------- W swizzle body ----------------
__device__ __forceinline__ void wswz_body(const float* __restrict__ W, unsigned short* __restrict__ out,
                                          int DOUT, int tid) {
    int lane = tid & 63;
    int g = tid >> 6;
    int NT = DOUT >> 4;
    int tile = g % NT, kstep = g / NT;
    int q = lane >> 4, c = lane & 15;
    int n_ = tile * 16 + c;
    unsigned short v[8];
#pragma unroll
    for (int j = 0; j < 8; ++j) {
        int k = kstep * 32 + q * 8 + j;
        v[j] = f2bf(W[k * DOUT + n_]);
    }
    uint4 o;
    o.x = (unsigned)v[0] | ((unsigned)v[1] << 16);
    o.y = (unsigned)v[2] | ((unsigned)v[3] << 16);
    o.z = (unsigned)v[4] | ((unsigned)v[5] << 16);
    o.w = (unsigned)v[6] | ((unsigned)v[7] << 16);
    *(uint4*)(out + (size_t)tid * 8) = o;
}

// ---------------- K1: per-block LDS histogram (rank capture, NO device atomics) + W swizzles ------
__global__ __launch_bounds__(256) void histswz_kernel(
    const int* __restrict__ dstv, unsigned* __restrict__ hist32, unsigned char* __restrict__ rank8,
    int E, int hb, int nw,
    const float* __restrict__ W0, const float* __restrict__ W1, const float* __restrict__ W2,
    unsigned short* __restrict__ wz0, unsigned short* __restrict__ wz1, unsigned short* __restrict__ wz2)
{
    __shared__ unsigned bins[12544];   // 50 KB (n=50000 -> 12544 packed words)
    int b = blockIdx.x;
    if (b >= hb) {
        int wb = b - hb;
        if (wb < 8)       wswz_body(W0, wz0, 128, wb * 256 + threadIdx.x);
        else if (wb < 16) wswz_body(W1, wz1, 128, (wb - 8) * 256 + threadIdx.x);
        else {
            int tid = (wb - 16) * 256 + threadIdx.x;
            if (tid < 1024) wswz_body(W2, wz2, 64, tid);
        }
        return;
    }
    int tid = threadIdx.x;
    int nw4 = nw >> 2;
    bool v4ok = (nw & 3) == 0;
    if (v4ok) {
        uint4 z4; z4.x = z4.y = z4.z = z4.w = 0u;
        uint4* b4 = (uint4*)bins;
        for (int i = tid; i < nw4; i += 256) b4[i] = z4;
    } else {
        for (int i = tid; i < nw; i += 256) bins[i] = 0u;
    }
    __syncthreads();
    int base = b * 4096;
#pragma unroll
    for (int j = 0; j < 4; ++j) {
        int e0 = base + j * 1024 + tid * 4;
        if (e0 + 3 < E) {
            int4 d4 = *(const int4*)(dstv + e0);
            unsigned r0, r1, r2, r3;
            { int sh = (d4.x & 3) * 8; r0 = (atomicAdd(&bins[d4.x >> 2], 1u << sh) >> sh) & 0xffu; }
            { int sh = (d4.y & 3) * 8; r1 = (atomicAdd(&bins[d4.y >> 2], 1u << sh) >> sh) & 0xffu; }
            { int sh = (d4.z & 3) * 8; r2 = (atomicAdd(&bins[d4.z >> 2], 1u << sh) >> sh) & 0xffu; }
            { int sh = (d4.w & 3) * 8; r3 = (atomicAdd(&bins[d4.w >> 2], 1u << sh) >> sh) & 0xffu; }
            *(unsigned*)(rank8 + e0) = r0 | (r1 << 8) | (r2 << 16) | (r3 << 24);
        } else {
            for (int k = 0; k < 4; ++k) {
                int e = e0 + k;
                if (e < E) {
                    int d = dstv[e];
                    int sh = (d & 3) * 8;
                    rank8[e] = (unsigned char)((atomicAdd(&bins[d >> 2], 1u << sh) >> sh) & 0xffu);
                }
            }
        }
    }
    __syncthreads();
    unsigned* hrow = hist32 + (size_t)b * nw;
    if (v4ok) {
        uint4* h4 = (uint4*)hrow;
        const uint4* s4 = (const uint4*)bins;
        for (int i = tid; i < nw4; i += 256) h4[i] = s4[i];
    } else {
        for (int i = tid; i < nw; i += 256) hrow[i] = bins[i];
    }
}

// ---------------- K3: single-pass scan of counts -> row_ptr ----------------
__global__ __launch_bounds__(1024) void scan1_kernel(const int* __restrict__ counts,
                                                     int* __restrict__ excl,
                                                     int* __restrict__ totals, int n) {
    __shared__ int sm[BS_SCAN];
    int tid = threadIdx.x;
    int i = blockIdx.x * BS_SCAN + tid;
    int v = (i < n) ? counts[i] : 0;
    int val = v;
    sm[tid] = val;
    for (int off = 1; off < BS_SCAN; off <<= 1) {
        __syncthreads();
        int t = (tid >= off) ? sm[tid - off] : 0;
        __syncthreads();
        val += t; sm[tid] = val;
    }
    if (i < n) excl[i] = val - v;
    if (tid == BS_SCAN - 1) totals[blockIdx.x] = val;
}

__global__ __launch_bounds__(1024) void scan23_kernel(int* __restrict__ row_ptr,
                                                      const int* __restrict__ totals,
                                                      int n, int E, int nb) {
    __shared__ int s_off;
    int tid = threadIdx.x;
    if (tid < 64) {
        int v = (tid < blockIdx.x && tid < nb) ? totals[tid] : 0;
#pragma unroll
        for (int off = 32; off; off >>= 1) v += __shfl_xor(v, off);
        if (tid == 0) s_off = v;
    }
    __syncthreads();
    int off = s_off;
    int i = blockIdx.x * BS_SCAN + tid;
    if (i < n) row_ptr[i] += off;
    if (i == 0) row_ptr[n] = E;
}

// ---------------- GEMM body (bf16 MFMA) + attention dots, 2-chunk LDS ----------------
template<int DOUT, bool ABF>
__device__ __forceinline__ void gemm_body(
    int bid, const void* __restrict__ Xv, const unsigned short* __restrict__ Wswz,
    const float* __restrict__ avs, const float* __restrict__ avd,
    unsigned* __restrict__ Hout, float* __restrict__ as_out, float* __restrict__ ad_out,
    int n, float* __restrict__ smemw)
{
    constexpr int NT = DOUT / 16;
    constexpr int NCH = NT / 4;          // 2 for DOUT=128, 1 for DOUT=64
    int lane = threadIdx.x & 63;
    int w = threadIdx.x >> 6;
    int q = lane >> 4, c = lane & 15;
    int rowbase = bid * 64 + w * 16;
    int arow = rowbase + c;

    f32x4 acc[NT];
#pragma unroll
    for (int t = 0; t < NT; ++t) acc[t] = (f32x4){0.f, 0.f, 0.f, 0.f};

#pragma unroll
    for (int ks = 0; ks < 4; ++ks) {
        bfrag a = (bfrag)0;
        int k0 = ks * 32 + q * 8;
        if (ABF) {
            if (arow < n) a = *(const bfrag*)((const unsigned short*)Xv + (size_t)arow * 128 + k0);
        } else {
            if (arow < n) {
                const float* xp = (const float*)Xv + (size_t)arow * 128 + k0;
                float4 x0 = *(const float4*)xp, x1 = *(const float4*)(xp + 4);
                a[0] = (short)f2bf(x0.x); a[1] = (short)f2bf(x0.y);
                a[2] = (short)f2bf(x0.z); a[3] = (short)f2bf(x0.w);
                a[4] = (short)f2bf(x1.x); a[5] = (short)f2bf(x1.y);
                a[6] = (short)f2bf(x1.z); a[7] = (short)f2bf(x1.w);
            }
        }
#pragma unroll
        for (int t = 0; t < NT; ++t) {
            bfrag b = *(const bfrag*)(Wswz + ((size_t)(ks * NT + t) * 64 + lane) * 8);
            acc[t] = __builtin_amdgcn_mfma_f32_16x16x32_bf16(a, b, acc[t], 0, 0, 0);
        }
    }

    // per-wave transpose buffer: 16 rows x 68 floats (64 cols + pad) = 4352 B/wave
    float* sm = smemw + w * (16 * 68);
    int dr = lane >> 2;
    int c0 = (lane & 3) * 16;
    float s = 0.f, d = 0.f;

#pragma unroll
    for (int ch = 0; ch < NCH; ++ch) {
        if (ch) {
            // drain chunk-0 LDS reads before overwriting (WAR within wave)
            asm volatile("s_waitcnt lgkmcnt(0)" ::: "memory");
            __builtin_amdgcn_wave_barrier();
        }
#pragma unroll
        for (int t = 0; t < 4; ++t)
#pragma unroll
            for (int r = 0; r < 4; ++r)
                sm[(q * 4 + r) * 68 + t * 16 + c] = acc[ch * 4 + t][r];
        __builtin_amdgcn_wave_barrier();

        // bf16 store of this 64-col chunk
#pragma unroll
        for (int it = 0; it < 4; ++it) {
            int r = it * 4 + q;
            int grow = rowbase + r;
            float4 v = *(const float4*)(sm + r * 68 + c * 4);
            uint2 o;
            o.x = (unsigned)f2bf(v.x) | ((unsigned)f2bf(v.y) << 16);
            o.y = (unsigned)f2bf(v.z) | ((unsigned)f2bf(v.w) << 16);
            if (grow < n) *(uint2*)(Hout + (size_t)grow * (DOUT / 2) + ch * 32 + c * 2) = o;
        }
        // attention-dot partials for this chunk
#pragma unroll
        for (int j = 0; j < 16; j += 4) {
            float4 hv = *(const float4*)(sm + dr * 68 + c0 + j);
            float4 av = *(const float4*)(avs + ch * 64 + c0 + j);
            float4 dv = *(const float4*)(avd + ch * 64 + c0 + j);
            s += hv.x * av.x + hv.y * av.y + hv.z * av.z + hv.w * av.w;
            d += hv.x * dv.x + hv.y * dv.y + hv.z * dv.z + hv.w * dv.w;
        }
    }

    s += __shfl_down(s, 2); s += __shfl_down(s, 1);
    d += __shfl_down(d, 2); d += __shfl_down(d, 1);
    int grow = rowbase + dr;
    if ((lane & 3) == 0 && grow < n) { as_out[grow] = s; ad_out[grow] = d; }
}

// ---------------- K2: LDS-transpose column scan of histograms + layer-0 GEMM, one dispatch ------
__global__ __launch_bounds__(256) void scangemm0_kernel(
    const unsigned* __restrict__ hist32, unsigned* __restrict__ off32,
    int* __restrict__ counts, int hb, int nw, int sb,
    const float* __restrict__ X, const unsigned short* __restrict__ wz0,
    const float* __restrict__ avs, const float* __restrict__ avd,
    unsigned* __restrict__ Hout, float* __restrict__ as_out, float* __restrict__ ad_out, int n)
{
    __shared__ unsigned smem[HB_MAX * (WPB + 1)];   // 160*33*4 = 21120 B
    int b = blockIdx.x;
    if (b < sb) {
        unsigned (*tile)[WPB + 1] = (unsigned (*)[WPB + 1])smem;
        int tid = threadIdx.x;
        int w0 = b * WPB;
        int wl = tid & 31;
        int w = w0 + wl;
        for (int r = tid >> 5; r < hb; r += 8)
            tile[r][wl] = (w < nw) ? hist32[(size_t)r * nw + w] : 0u;
        __syncthreads();
        if (tid < WPB) {
            unsigned run = 0;
            for (int r = 0; r < hb; ++r) {
                unsigned v = tile[r][tid];
                tile[r][tid] = run;    // exclusive prefix per 8-bit field
                run += v;              // no inter-field carry: per-node totals << 256
            }
            int ww = w0 + tid;
            if (ww < nw) {
                int i0 = ww * 4;
                int4 cv;
                cv.x = (int)(run & 0xffu);         cv.y = (int)((run >> 8) & 0xffu);
                cv.z = (int)((run >> 16) & 0xffu); cv.w = (int)((run >> 24) & 0xffu);
                if (i0 + 3 < n) *(int4*)(counts + i0) = cv;
                else {
                    if (i0 < n)     counts[i0]     = cv.x;
                    if (i0 + 1 < n) counts[i0 + 1] = cv.y;
                    if (i0 + 2 < n) counts[i0 + 2] = cv.z;
                    if (i0 + 3 < n) counts[i0 + 3] = cv.w;
                }
            }
        }
        __syncthreads();
        for (int r = tid >> 5; r < hb; r += 8)
            if (w < nw) off32[(size_t)r * nw + w] = tile[r][wl];
        return;
    }
    gemm_body<128, false>(b - sb, X, wz0, avs, avd, Hout, as_out, ad_out, n, (float*)smem);
}

// ---------------- standalone GEMM layers 1/2 (A = bf16 global) ----------------
template<int DOUT>
__global__ __launch_bounds__(256) void gemm_kernel(
    const unsigned* __restrict__ Xb, const unsigned short* __restrict__ Wswz,
    const float* __restrict__ avs, const float* __restrict__ avd,
    unsigned* __restrict__ Hout, float* __restrict__ as_out, float* __restrict__ ad_out, int n)
{
    __shared__ float smem[4 * 16 * 68];
    gemm_body<DOUT, true>(blockIdx.x, Xb, Wswz, avs, avd, Hout, as_out, ad_out, n, smem);
}

// ---------------- K5: fully atomic-free scatter: col[row_ptr[d]+off[b][d]+rank[e]] = s --------
__global__ __launch_bounds__(256) void scatter_kernel(
    const int* __restrict__ ei, const unsigned char* __restrict__ rank8,
    const unsigned* __restrict__ off32, const int* __restrict__ row_ptr,
    unsigned short* __restrict__ col, int E, int nw)
{
    int e0 = (blockIdx.x * 256 + (int)threadIdx.x) * 4;
    if (e0 + 3 < E) {
        int4 s4 = *(const int4*)(ei + e0);
        int4 d4 = *(const int4*)(ei + E + e0);
        unsigned r4 = *(const unsigned*)(rank8 + e0);
        size_t bb = (size_t)(e0 >> 12) * nw;   // e0..e0+3 share the 4096-edge chunk
        unsigned o0 = (off32[bb + (d4.x >> 2)] >> ((d4.x & 3) * 8)) & 0xffu;
        unsigned o1 = (off32[bb + (d4.y >> 2)] >> ((d4.y & 3) * 8)) & 0xffu;
        unsigned o2 = (off32[bb + (d4.z >> 2)] >> ((d4.z & 3) * 8)) & 0xffu;
        unsigned o3 = (off32[bb + (d4.w >> 2)] >> ((d4.w & 3) * 8)) & 0xffu;
        col[row_ptr[d4.x] + (int)o0 + (int)(r4 & 0xffu)]         = (unsigned short)s4.x;
        col[row_ptr[d4.y] + (int)o1 + (int)((r4 >> 8) & 0xffu)]  = (unsigned short)s4.y;
        col[row_ptr[d4.z] + (int)o2 + (int)((r4 >> 16) & 0xffu)] = (unsigned short)s4.z;
        col[row_ptr[d4.w] + (int)o3 + (int)((r4 >> 24) & 0xffu)] = (unsigned short)s4.w;
    } else {
        for (int k = 0; k < 4; ++k) {
            int e = e0 + k;
            if (e < E) {
                int d = ei[E + e];
                unsigned o = (off32[(size_t)(e >> 12) * nw + (d >> 2)] >> ((d & 3) * 8)) & 0xffu;
                col[row_ptr[d] + (int)o + (int)rank8[e]] = (unsigned short)ei[e];
            }
        }
    }
}

// ---------------- aggregation, 128-wide bf16 h, SiLU, bf16 out ----------------
// 16 lanes per node (4 nodes/wave, 16 nodes/block): R5-proven.
__global__ __launch_bounds__(256) void agg128_kernel(
    const unsigned* __restrict__ Hb, const float* __restrict__ as_v,
    const float* __restrict__ ad_v, const float* __restrict__ bias,
    const int* __restrict__ row_ptr, const unsigned short* __restrict__ col,
    unsigned* __restrict__ outb, int n)
{
    int lane = threadIdx.x & 63;
    int g = lane >> 4, i = lane & 15;
    int node = blockIdx.x * 16 + (threadIdx.x >> 6) * 4 + g;
    if (node >= n) return;
    int beg = row_ptr[node], end = row_ptr[node + 1];
    float adv = ad_v[node];
    float c_self = __expf(fminf(lrelu(as_v[node] + adv), 60.f));

    uint4 hs = *(const uint4*)(Hb + (size_t)node * 64 + i * 4);
    float acc[8];
    acc[0] = c_self * bf2f_lo(hs.x); acc[1] = c_self * bf2f_hi(hs.x);
    acc[2] = c_self * bf2f_lo(hs.y); acc[3] = c_self * bf2f_hi(hs.y);
    acc[4] = c_self * bf2f_lo(hs.z); acc[5] = c_self * bf2f_hi(hs.z);
    acc[6] = c_self * bf2f_lo(hs.w); acc[7] = c_self * bf2f_hi(hs.w);
    float dsum = (i == 0) ? c_self : 0.f;
    int lanebase = g * 16;

    for (int cb = beg; cb < end; cb += 16) {
        int idx = cb + i;
        int sreg = 0; float creg = 0.f;
        if (idx < end) {
            sreg = col[idx];
            creg = __expf(fminf(lrelu(as_v[sreg] + adv), 60.f));
        }
        dsum += creg;
        int cnt = end - cb; if (cnt > 16) cnt = 16;
        for (int k = 0; k < cnt; k += 4) {
            int s0 = __shfl(sreg, lanebase + k);
            int s1 = __shfl(sreg, lanebase + k + 1);
            int s2 = __shfl(sreg, lanebase + k + 2);
            int s3 = __shfl(sreg, lanebase + k + 3);
            float c0 = __shfl(creg, lanebase + k);       // lanes >= cnt carry creg=0
            float c1 = __shfl(creg, lanebase + k + 1);
            float c2 = __shfl(creg, lanebase + k + 2);
            float c3 = __shfl(creg, lanebase + k + 3);
            uint4 h0 = *(const uint4*)(Hb + (size_t)s0 * 64 + i * 4);
            uint4 h1 = *(const uint4*)(Hb + (size_t)s1 * 64 + i * 4);
            uint4 h2 = *(const uint4*)(Hb + (size_t)s2 * 64 + i * 4);
            uint4 h3 = *(const uint4*)(Hb + (size_t)s3 * 64 + i * 4);
            acc[0] += c0 * bf2f_lo(h0.x); acc[1] += c0 * bf2f_hi(h0.x);
            acc[2] += c0 * bf2f_lo(h0.y); acc[3] += c0 * bf2f_hi(h0.y);
            acc[4] += c0 * bf2f_lo(h0.z); acc[5] += c0 * bf2f_hi(h0.z);
            acc[6] += c0 * bf2f_lo(h0.w); acc[7] += c0 * bf2f_hi(h0.w);
            acc[0] += c1 * bf2f_lo(h1.x); acc[1] += c1 * bf2f_hi(h1.x);
            acc[2] += c1 * bf2f_lo(h1.y); acc[3] += c1 * bf2f_hi(h1.y);
            acc[4] += c1 * bf2f_lo(h1.z); acc[5] += c1 * bf2f_hi(h1.z);
            acc[6] += c1 * bf2f_lo(h1.w); acc[7] += c1 * bf2f_hi(h1.w);
            acc[0] += c2 * bf2f_lo(h2.x); acc[1] += c2 * bf2f_hi(h2.x);
            acc[2] += c2 * bf2f_lo(h2.y); acc[3] += c2 * bf2f_hi(h2.y);
            acc[4] += c2 * bf2f_lo(h2.z); acc[5] += c2 * bf2f_hi(h2.z);
            acc[6] += c2 * bf2f_lo(h2.w); acc[7] += c2 * bf2f_hi(h2.w);
            acc[0] += c3 * bf2f_lo(h3.x); acc[1] += c3 * bf2f_hi(h3.x);
            acc[2] += c3 * bf2f_lo(h3.y); acc[3] += c3 * bf2f_hi(h3.y);
            acc[4] += c3 * bf2f_lo(h3.z); acc[5] += c3 * bf2f_hi(h3.z);
            acc[6] += c3 * bf2f_lo(h3.w); acc[7] += c3 * bf2f_hi(h3.w);
        }
    }

#pragma unroll
    for (int off = 8; off; off >>= 1) dsum += __shfl_xor(dsum, off);
    float inv = 1.f / dsum;

    float4 b0v = *(const float4*)(bias + i * 8);
    float4 b1v = *(const float4*)(bias + i * 8 + 4);
    float v0 = acc[0] * inv + b0v.x, v1 = acc[1] * inv + b0v.y;
    float v2 = acc[2] * inv + b0v.z, v3 = acc[3] * inv + b0v.w;
    float v4 = acc[4] * inv + b1v.x, v5 = acc[5] * inv + b1v.y;
    float v6 = acc[6] * inv + b1v.z, v7 = acc[7] * inv + b1v.w;
    v0 /= (1.f + __expf(-v0)); v1 /= (1.f + __expf(-v1));
    v2 /= (1.f + __expf(-v2)); v3 /= (1.f + __expf(-v3));
    v4 /= (1.f + __expf(-v4)); v5 /= (1.f + __expf(-v5));
    v6 /= (1.f + __expf(-v6)); v7 /= (1.f + __expf(-v7));
    uint4 o;
    o.x = (unsigned)f2bf(v0) | ((unsigned)f2bf(v1) << 16);
    o.y = (unsigned)f2bf(v2) | ((unsigned)f2bf(v3) << 16);
    o.z = (unsigned)f2bf(v4) | ((unsigned)f2bf(v5) << 16);
    o.w = (unsigned)f2bf(v6) | ((unsigned)f2bf(v7) << 16);
    *(uint4*)(outb + (size_t)node * 64 + i * 4) = o;
}

// ---------------- final aggregation: bf16 h [n,64], log_softmax, fp32 out ----------------
__global__ __launch_bounds__(256) void agg64_kernel(
    const unsigned* __restrict__ Hb, const float* __restrict__ as_v,
    const float* __restrict__ ad_v, const float* __restrict__ bias,
    const int* __restrict__ row_ptr, const unsigned short* __restrict__ col,
    float* __restrict__ out, int n)
{
    int lane = threadIdx.x & 63;
    int g = lane >> 4, i = lane & 15;
    int node = blockIdx.x * 16 + (threadIdx.x >> 6) * 4 + g;
    if (node >= n) return;
    int beg = row_ptr[node], end = row_ptr[node + 1];
    float adv = ad_v[node];
    float c_self = __expf(fminf(lrelu(as_v[node] + adv), 60.f));

    uint2 hs = *(const uint2*)(Hb + (size_t)node * 32 + i * 2);
    float acc[4];
    acc[0] = c_self * bf2f_lo(hs.x); acc[1] = c_self * bf2f_hi(hs.x);
    acc[2] = c_self * bf2f_lo(hs.y); acc[3] = c_self * bf2f_hi(hs.y);
    float dsum = (i == 0) ? c_self : 0.f;
    int lanebase = g * 16;

    for (int cb = beg; cb < end; cb += 16) {
        int idx = cb + i;
        int sreg = 0; float creg = 0.f;
        if (idx < end) {
            sreg = col[idx];
            creg = __expf(fminf(lrelu(as_v[sreg] + adv), 60.f));
        }
        dsum += creg;
        int cnt = end - cb; if (cnt > 16) cnt = 16;
        for (int k = 0; k < cnt; k += 4) {
            int s0 = __shfl(sreg, lanebase + k);
            int s1 = __shfl(sreg, lanebase + k + 1);
            int s2 = __shfl(sreg, lanebase + k + 2);
            int s3 = __shfl(sreg, lanebase + k + 3);
            float c0 = __shfl(creg, lanebase + k);
            float c1 = __shfl(creg, lanebase + k + 1);
            float c2 = __shfl(creg, lanebase + k + 2);
            float c3 = __shfl(creg, lanebase + k + 3);
            uint2 h0 = *(const uint2*)(Hb + (size_t)s0 * 32 + i * 2);
            uint2 h1 = *(const uint2*)(Hb + (size_t)s1 * 32 + i * 2);
            uint2 h2 = *(const uint2*)(Hb + (size_t)s2 * 32 + i * 2);
            uint2 h3 = *(const uint2*)(Hb + (size_t)s3 * 32 + i * 2);
            acc[0] += c0 * bf2f_lo(h0.x); acc[1] += c0 * bf2f_hi(h0.x);
            acc[2] += c0 * bf2f_lo(h0.y); acc[3] += c0 * bf2f_hi(h0.y);
            acc[0] += c1 * bf2f_lo(h1.x); acc[1] += c1 * bf2f_hi(h1.x);
            acc[2] += c1 * bf2f_lo(h1.y); acc[3] += c1 * bf2f_hi(h1.y);
            acc[0] += c2 * bf2f_lo(h2.x); acc[1] += c2 * bf2f_hi(h2.x);
            acc[2] += c2 * bf2f_lo(h2.y); acc[3] += c2 * bf2f_hi(h2.y);
            acc[0] += c3 * bf2f_lo(h3.x); acc[1] += c3 * bf2f_hi(h3.x);
            acc[2] += c3 * bf2f_lo(h3.y); acc[3] += c3 * bf2f_hi(h3.y);
        }
    }

#pragma unroll
    for (int off = 8; off; off >>= 1) dsum += __shfl_xor(dsum, off);
    float inv = 1.f / dsum;

    float4 bv = *(const float4*)(bias + i * 4);
    float v0 = acc[0] * inv + bv.x, v1 = acc[1] * inv + bv.y;
    float v2 = acc[2] * inv + bv.z, v3 = acc[3] * inv + bv.w;
    float mx = fmaxf(fmaxf(v0, v1), fmaxf(v2, v3));
#pragma unroll
    for (int off = 8; off; off >>= 1) mx = fmaxf(mx, __shfl_xor(mx, off));
    float sum = __expf(v0 - mx) + __expf(v1 - mx) + __expf(v2 - mx) + __expf(v3 - mx);
#pragma unroll
    for (int off = 8; off; off >>= 1) sum += __shfl_xor(sum, off);
    float ls = mx + logf(sum);
    float4 o = make_float4(v0 - ls, v1 - ls, v2 - ls, v3 - ls);
    *(float4*)(out + (size_t)node * 64 + i * 4) = o;
}

extern "C" void kernel_launch(void* const* d_in, const int* in_sizes, int n_in,
                              void* d_out, int out_size, void* d_ws, size_t ws_size,
                              hipStream_t stream) {
    const float* x   = (const float*)d_in[0];
    const int*   ei  = (const int*)d_in[1];
    const float* W0  = (const float*)d_in[2];
    const float* as0 = (const float*)d_in[3];
    const float* ad0 = (const float*)d_in[4];
    const float* b0  = (const float*)d_in[5];
    const float* W1  = (const float*)d_in[6];
    const float* as1 = (const float*)d_in[7];
    const float* ad1 = (const float*)d_in[8];
    const float* b1  = (const float*)d_in[9];
    const float* W2  = (const float*)d_in[10];
    const float* as2 = (const float*)d_in[11];
    const float* ad2 = (const float*)d_in[12];
    const float* b2  = (const float*)d_in[13];

    int n = in_sizes[0] / 128;
    int E = in_sizes[1] / 2;
    const int* dstv = ei + E;

    int hb = (E + 4095) >> 12;              // histogram blocks (4096 edges each), 147 <= HB_MAX
    int nw = (n + 3) >> 2;                  // packed u32 words (4 nodes per word)

    char* wsp = (char*)d_ws;
    auto alloc = [&](size_t bytes) {
        char* p = wsp;
        wsp += (bytes + 255) & ~(size_t)255;
        return p;
    };
    int*   counts  = (int*)alloc((size_t)n * 4);
    int*   row_ptr = (int*)alloc((size_t)(n + 1) * 4);
    int*   totals  = (int*)alloc(256 * 4);
    unsigned* hist32 = (unsigned*)alloc((size_t)hb * nw * 4);
    unsigned* off32  = (unsigned*)alloc((size_t)hb * nw * 4);
    unsigned char* rank8 = (unsigned char*)alloc((size_t)E);
    unsigned short* col = (unsigned short*)alloc((size_t)E * 2);
    unsigned short* wz0 = (unsigned short*)alloc(128 * 128 * 2);
    unsigned short* wz1 = (unsigned short*)alloc(128 * 128 * 2);
    unsigned short* wz2 = (unsigned short*)alloc(128 * 64 * 2);
    unsigned* hb0  = (unsigned*)alloc((size_t)n * 64 * 4);   // [n,128] bf16 (pre-agg h)
    unsigned* hb1  = (unsigned*)alloc((size_t)n * 64 * 4);   // [n,128] bf16
    unsigned* hf   = (unsigned*)alloc((size_t)n * 32 * 4);   // [n,64]  bf16
    unsigned* xb   = (unsigned*)alloc((size_t)n * 64 * 4);   // [n,128] bf16 (agg out)
    float*    asbA = (float*)alloc((size_t)n * 4);
    float*    adbA = (float*)alloc((size_t)n * 4);
    float*    asbB = (float*)alloc((size_t)n * 4);
    float*    adbB = (float*)alloc((size_t)n * 4);

    int gemmb = (n + 63) / 64;
    int nodeb = (n + 15) / 16;              // 16 nodes/block (16 lanes/node)
    int nb  = (n + BS_SCAN - 1) / BS_SCAN;  // 49 <= 64
    int sb  = (nw + WPB - 1) / WPB;         // transpose-scan blocks (392)
    int scb = (E + 1023) / 1024;            // scatter blocks (4 edges/thread)

    // K1: LDS histogram + rank8 (no device atomics), with W swizzles riding along
    histswz_kernel<<<hb + 20, 256, 0, stream>>>(dstv, hist32, rank8, E, hb, nw,
                                                W0, W1, W2, wz0, wz1, wz2);
    // K2: cross-block offset scan (LDS-transpose, parallel) + layer-0 GEMM + dots
    scangemm0_kernel<<<sb + gemmb, 256, 0, stream>>>(hist32, off32, counts, hb, nw, sb,
                                                     x, wz0, as0, ad0, hb0, asbA, adbA, n);
    scan1_kernel<<<nb, BS_SCAN, 0, stream>>>(counts, row_ptr, totals, n);
    scan23_kernel<<<nb, BS_SCAN, 0, stream>>>(row_ptr, totals, n, E, nb);
    // K5: fully atomic-free scatter
    scatter_kernel<<<scb, 256, 0, stream>>>(ei, rank8, off32, row_ptr, col, E, nw);
    // layer 0 agg
    agg128_kernel<<<nodeb, 256, 0, stream>>>(hb0, asbA, adbA, b0, row_ptr, col, xb, n);
    // layer 1 GEMM + agg
    gemm_kernel<128><<<gemmb, 256, 0, stream>>>(xb, wz1, as1, ad1, hb1, asbB, adbB, n);
    agg128_kernel<<<nodeb, 256, 0, stream>>>(hb1, asbB, adbB, b1, row_ptr, col, xb, n);
    // layer 2 GEMM + final agg
    gemm_kernel<64><<<gemmb, 256, 0, stream>>>(xb, wz2, as2, ad2, hf, asbA, adbA, n);
    agg64_kernel<<<nodeb, 256, 0, stream>>>(hf, asbA, adbA, b2, row_ptr, col, (float*)d_out, n);
}